// Round 1
// baseline (632.752 us; speedup 1.0000x reference)
//
#include <hip/hip_runtime.h>

// RelativePositionEncoding (AF3-style), B=1, N=1024, C_Z=128.
// out[i,j,:] = W_pos[d_res] + W_tok[d_tok] + same_ent*w_ent + W_ch[d_chain]
//
// Fused-table trick: d_tok != 65 iff (same_chain && same_res), and then
// d_res == 32 exactly. d_chain != 5 iff same_ent. So the sum is always
// Tfused[row] + T3[crow] with
//   Tfused[dt]    = W_pos[32] + W_tok[dt]     (rows 0..65)
//   Tfused[66+dr] = W_pos[dr] + W_tok[65]     (rows 66..131)
//   T3[dc]        = W_ch[dc] + w_ent          (rows 132..136)
//   T3[5]         = W_ch[5]                   (row 137)
// 138 rows * 128 f32 = 70656 B in LDS (gfx950 has 160 KiB/CU).

#define RMAX 32
#define SMAX 2
#define CZ 128
#define TJ 512          // j-tile per block
#define NROWS 138       // fused table rows
#define BLOCK 256

__global__ __launch_bounds__(BLOCK) void relpos_kernel(
    const int* __restrict__ asym, const int* __restrict__ resi,
    const int* __restrict__ ent,  const int* __restrict__ sym,
    const int* __restrict__ tok,  const float* __restrict__ W,
    float* __restrict__ out, int N)
{
    __shared__ float4 sW4[NROWS * 32];   // 70656 B, row r at sW4[r*32 .. r*32+31]
    __shared__ int2   sOff[TJ];          // per-j (row<<5, crow<<5) float4 offsets

    const int tid = threadIdx.x;
    const int i   = blockIdx.y;
    const int j0  = blockIdx.x * TJ;

    const float4* __restrict__ W4 = reinterpret_cast<const float4*>(W);
    // Original W rows: W_pos 0..65, W_tok 66..131, w_ent 132, W_ch 133..138.

    // --- build fused tables in LDS ---
    for (int t = tid; t < NROWS * 32; t += BLOCK) {
        const int row = t >> 5, cc = t & 31;
        float4 a, b;
        if (row < 66) {                       // W_pos[32] + W_tok[row]
            a = W4[32 * 32 + cc];
            b = W4[(66 + row) * 32 + cc];
        } else if (row < 132) {               // W_pos[row-66] + W_tok[65]
            a = W4[(row - 66) * 32 + cc];
            b = W4[131 * 32 + cc];
        } else if (row < 137) {               // W_ch[row-132] + w_ent
            a = W4[(133 + (row - 132)) * 32 + cc];
            b = W4[132 * 32 + cc];
        } else {                              // W_ch[5]
            a = W4[138 * 32 + cc];
            b = make_float4(0.f, 0.f, 0.f, 0.f);
        }
        sW4[t] = make_float4(a.x + b.x, a.y + b.y, a.z + b.z, a.w + b.w);
    }

    // --- per-j fused row offsets (i is fixed for the whole block) ---
    const int ai = asym[i], ri = resi[i], ei = ent[i], si = sym[i], ti = tok[i];
    for (int t = tid; t < TJ; t += BLOCK) {
        const int j = j0 + t;
        const int aj = asym[j], rj = resi[j], ej = ent[j], sj = sym[j], tj = tok[j];
        int row;
        if (ai == aj) {
            if (ri == rj) {
                int dt = ti - tj + RMAX;
                dt = dt < 0 ? 0 : (dt > 2 * RMAX ? 2 * RMAX : dt);
                row = dt;                      // Tfused[dt]
            } else {
                int dr = ri - rj + RMAX;
                dr = dr < 0 ? 0 : (dr > 2 * RMAX ? 2 * RMAX : dr);
                row = 66 + dr;                 // Tfused[66+dr]
            }
        } else {
            row = 131;                         // dr==65 case
        }
        int crow;
        if (ei == ej) {
            int dc = si - sj + SMAX;
            dc = dc < 0 ? 0 : (dc > 2 * SMAX ? 2 * SMAX : dc);
            crow = 132 + dc;
        } else {
            crow = 137;
        }
        sOff[t] = make_int2(row << 5, crow << 5);
    }
    __syncthreads();

    // --- stream the output tile ---
    const int cc = tid & 31;   // float4 channel group, 0..31
    const int jl = tid >> 5;   // 0..7
    float4* __restrict__ out4 = reinterpret_cast<float4*>(out);
    const size_t base = ((size_t)i * N + j0) * 32 + cc;

    #pragma unroll 4
    for (int jj = jl; jj < TJ; jj += 8) {
        const int2 off = sOff[jj];
        const float4 a = sW4[off.x + cc];
        const float4 b = sW4[off.y + cc];
        out4[base + (size_t)jj * 32] =
            make_float4(a.x + b.x, a.y + b.y, a.z + b.z, a.w + b.w);
    }
}

extern "C" void kernel_launch(void* const* d_in, const int* in_sizes, int n_in,
                              void* d_out, int out_size, void* d_ws, size_t ws_size,
                              hipStream_t stream) {
    const int* asym = (const int*)d_in[0];
    const int* resi = (const int*)d_in[1];
    const int* ent  = (const int*)d_in[2];
    const int* sym  = (const int*)d_in[3];
    const int* tok  = (const int*)d_in[4];
    const float* W  = (const float*)d_in[5];
    float* out = (float*)d_out;

    const int N = in_sizes[0];          // B*N with B=1
    dim3 grid(N / TJ, N);               // (2, 1024)
    relpos_kernel<<<grid, BLOCK, 0, stream>>>(asym, resi, ent, sym, tok, W, out, N);
}

// Round 2
// 607.760 us; speedup vs baseline: 1.0411x; 1.0411x over previous
//
#include <hip/hip_runtime.h>

// RelativePositionEncoding (AF3-style), B=1, N=1024, C_Z=128. Pure HBM-write-bound:
// 537 MB out, roofline ~85 us @ 6.3 TB/s.
//
// Fused-table trick (verified absmax=0 in R1): d_tok != 65 iff (same_chain &&
// same_res), and then d_res == 32 exactly; d_chain != 5 iff same_ent. So
// out[i,j,:] = Tfused[row] + T3[crow] with
//   Tfused[dt]    = W_pos[32] + W_tok[dt]     (rows 0..65)
//   Tfused[66+dr] = W_pos[dr] + W_tok[65]     (rows 66..131)
//   T3[dc]        = W_ch[dc] + w_ent          (rows 132..136)
//   T3[5]         = W_ch[5]                   (row 137)
//
// R2 restructure: 4-way channel split (32 ch = 8 float4 per block) so the LDS
// table slice is 17.7 KB; full-row j sweep with packed 1-int offsets (4 KB).
// Total ~21.8 KB LDS -> 7 blocks/CU = 28 waves/CU (vs 2 blocks/8 waves in R1),
// to hide the LDS-chain latency feeding the store stream.

#define RMAX 32
#define SMAX 2
#define NROWS 138
#define BLOCK 256

__global__ __launch_bounds__(BLOCK) void relpos_kernel(
    const int* __restrict__ asym, const int* __restrict__ resi,
    const int* __restrict__ ent,  const int* __restrict__ sym,
    const int* __restrict__ tok,  const float* __restrict__ W,
    float* __restrict__ out, int N)
{
    __shared__ float4 sW[NROWS * 8];   // 17,664 B: this block's 8 float4-groups per row
    __shared__ int    sOff[1024];      // packed (row*8) | (crow*8 << 16), float4-elem offsets

    const int tid = threadIdx.x;
    const int q   = blockIdx.x;        // channel quad 0..3 (float4 groups q*8 .. q*8+7)
    const int i   = blockIdx.y;

    const float4* __restrict__ W4 = reinterpret_cast<const float4*>(W);
    // Original W rows: W_pos 0..65, W_tok 66..131, w_ent 132, W_ch 133..138.

    // --- build this block's channel slice of the fused tables ---
    for (int t = tid; t < NROWS * 8; t += BLOCK) {
        const int row = t >> 3;
        const int g   = q * 8 + (t & 7);   // global float4 channel group 0..31
        float4 a, b;
        if (row < 66) {                      // W_pos[32] + W_tok[row]
            a = W4[32 * 32 + g];
            b = W4[(66 + row) * 32 + g];
        } else if (row < 132) {              // W_pos[row-66] + W_tok[65]
            a = W4[(row - 66) * 32 + g];
            b = W4[131 * 32 + g];
        } else if (row < 137) {              // W_ch[row-132] + w_ent  (133+(row-132)=row+1)
            a = W4[(row + 1) * 32 + g];
            b = W4[132 * 32 + g];
        } else {                             // W_ch[5]
            a = W4[138 * 32 + g];
            b = make_float4(0.f, 0.f, 0.f, 0.f);
        }
        sW[t] = make_float4(a.x + b.x, a.y + b.y, a.z + b.z, a.w + b.w);
    }

    // --- per-j packed fused row offsets (i fixed for the block) ---
    const int ai = asym[i], ri = resi[i], ei = ent[i], si = sym[i], ti = tok[i];
    for (int t = tid; t < N; t += BLOCK) {
        const int aj = asym[t], rj = resi[t], ej = ent[t], sj = sym[t], tj = tok[t];
        int row;
        if (ai == aj) {
            if (ri == rj) {
                int dt = ti - tj + RMAX;
                dt = dt < 0 ? 0 : (dt > 2 * RMAX ? 2 * RMAX : dt);
                row = dt;
            } else {
                int dr = ri - rj + RMAX;
                dr = dr < 0 ? 0 : (dr > 2 * RMAX ? 2 * RMAX : dr);
                row = 66 + dr;
            }
        } else {
            row = 131;
        }
        int crow;
        if (ei == ej) {
            int dc = si - sj + SMAX;
            dc = dc < 0 ? 0 : (dc > 2 * SMAX ? 2 * SMAX : dc);
            crow = 132 + dc;
        } else {
            crow = 137;
        }
        sOff[t] = (row << 3) | (crow << 19);   // row*8 in low 16, crow*8 in high 16
    }
    __syncthreads();

    // --- stream this block's 128 KB output slice ---
    const int cc = tid & 7;           // float4 group within slice, 0..7
    const int jl = tid >> 3;          // 0..31
    float4* __restrict__ out4 = reinterpret_cast<float4*>(out);
    const size_t base = (size_t)i * N * 32 + (size_t)(q * 8 + cc);

    #pragma unroll 8
    for (int jj = jl; jj < N; jj += 32) {
        const int off = sOff[jj];
        const float4 a = sW[(off & 0xffff) + cc];
        const float4 b = sW[(off >> 16) + cc];
        out4[base + (size_t)jj * 32] =
            make_float4(a.x + b.x, a.y + b.y, a.z + b.z, a.w + b.w);
    }
}

extern "C" void kernel_launch(void* const* d_in, const int* in_sizes, int n_in,
                              void* d_out, int out_size, void* d_ws, size_t ws_size,
                              hipStream_t stream) {
    const int* asym = (const int*)d_in[0];
    const int* resi = (const int*)d_in[1];
    const int* ent  = (const int*)d_in[2];
    const int* sym  = (const int*)d_in[3];
    const int* tok  = (const int*)d_in[4];
    const float* W  = (const float*)d_in[5];
    float* out = (float*)d_out;

    const int N = in_sizes[0];          // B*N with B=1 (N=1024)
    dim3 grid(4, N);                    // (channel quad, i)
    relpos_kernel<<<grid, BLOCK, 0, stream>>>(asym, resi, ent, sym, tok, W, out, N);
}

// Round 3
// 537.258 us; speedup vs baseline: 1.1777x; 1.1312x over previous
//
#include <hip/hip_runtime.h>

// RelativePositionEncoding (AF3-style), B=1, N=1024, C_Z=128. HBM-write-bound:
// 537 MB out, write roofline ~85 us @ 6.3 TB/s.
//
// Fused-table algebra (verified absmax=0 in R1/R2): d_tok != 65 iff
// (same_chain && same_res) and then d_res==32; d_chain != 5 iff same_ent.
// So out[i,j,:] is one of only 132*6 = 792 distinct rows:
//   out[i,j,:] = C[row*6 + crow], with
//     row  < 66 : W_pos[32]  + W_tok[row]        (same chain+res, dt=row)
//     row >= 66 : W_pos[row-66] + W_tok[65]      (dr = row-66; diff chain -> 131)
//     crow < 5  : W_ch[crow] + w_ent             (same entity)
//     crow == 5 : W_ch[5]
//
// R3 structure: K1 materializes all 792 combined rows (405 KB) into d_ws
// (L2/L3-resident). K2's hot loop is a pure gather-memcpy: 1 ds_read_b32
// (broadcast row offset) + 1 global_load_dwordx4 (L2 hit) + 1
// global_store_dwordx4 (contiguous 1024 B/wave). No adds, no b128 LDS chain,
// no 70 KB per-block table build -- mimics the fill kernel that demonstrably
// hits 6.3 TB/s on this write path.

#define RMAX 32
#define SMAX 2
#define TJ 512
#define BLOCK 256

// ---- K1: build the 792 x 128 combined-row table in d_ws ----
// grid 99 x 256 = 25344 = 792 rows * 32 float4
__global__ __launch_bounds__(BLOCK) void build_combo(
    const float* __restrict__ W, float4* __restrict__ C)
{
    const int t  = blockIdx.x * BLOCK + threadIdx.x;
    const int rc = t >> 5;          // combined row 0..791
    const int cc = t & 31;          // float4 group 0..31
    const int r  = rc / 6;          // 0..131
    const int c  = rc - r * 6;      // 0..5

    const float4* __restrict__ W4 = reinterpret_cast<const float4*>(W);
    // W rows: W_pos 0..65, W_tok 66..131, w_ent 132, W_ch 133..138.
    float4 a, b;
    if (r < 66) { a = W4[32 * 32 + cc];       b = W4[(66 + r) * 32 + cc]; }
    else        { a = W4[(r - 66) * 32 + cc]; b = W4[131 * 32 + cc];      }
    float4 d;
    if (c < 5) {
        const float4 e = W4[(133 + c) * 32 + cc];
        const float4 f = W4[132 * 32 + cc];
        d = make_float4(e.x + f.x, e.y + f.y, e.z + f.z, e.w + f.w);
    } else {
        d = W4[138 * 32 + cc];
    }
    C[rc * 32 + cc] = make_float4(a.x + b.x + d.x, a.y + b.y + d.y,
                                  a.z + b.z + d.z, a.w + b.w + d.w);
}

// ---- K2: stream the output; pure gather-memcpy hot loop ----
__global__ __launch_bounds__(BLOCK) void relpos_stream(
    const int* __restrict__ asym, const int* __restrict__ resi,
    const int* __restrict__ ent,  const int* __restrict__ sym,
    const int* __restrict__ tok,  const char* __restrict__ Cbytes,
    float* __restrict__ out, int N)
{
    __shared__ int sAddr[TJ];      // per-j byte offset into C (2 KB)

    const int tid = threadIdx.x;
    const int i   = blockIdx.y;
    const int j0  = blockIdx.x * TJ;

    // --- index build: (row*6+crow)*512 byte offsets for this j-tile ---
    const int ai = asym[i], ri = resi[i], ei = ent[i], si = sym[i], ti = tok[i];
    for (int t = tid; t < TJ; t += BLOCK) {
        const int j = j0 + t;
        const int aj = asym[j], rj = resi[j], ej = ent[j], sj = sym[j], tj = tok[j];
        int row;
        if (ai == aj) {
            if (ri == rj) {
                int dt = ti - tj + RMAX;
                dt = dt < 0 ? 0 : (dt > 2 * RMAX ? 2 * RMAX : dt);
                row = dt;
            } else {
                int dr = ri - rj + RMAX;
                dr = dr < 0 ? 0 : (dr > 2 * RMAX ? 2 * RMAX : dr);
                row = 66 + dr;
            }
        } else {
            row = 131;
        }
        int crow;
        if (ei == ej) {
            int dc = si - sj + SMAX;
            dc = dc < 0 ? 0 : (dc > 2 * SMAX ? 2 * SMAX : dc);
            crow = dc;
        } else {
            crow = 5;
        }
        sAddr[t] = (row * 6 + crow) << 9;   // *512 bytes per combined row
    }
    __syncthreads();

    // --- stream: wave = 2 rows x 512 B = contiguous 1024 B stores ---
    const int cc = tid & 31;   // float4 group within row
    const int jl = tid >> 5;   // 0..7
    float4* __restrict__ out4 = reinterpret_cast<float4*>(out);
    const size_t base = ((size_t)i * N + j0) * 32 + cc;

    #pragma unroll 8
    for (int jj = jl; jj < TJ; jj += 8) {
        const int off = sAddr[jj];
        const float4 v = *reinterpret_cast<const float4*>(
            Cbytes + off + (cc << 4));
        out4[base + (size_t)jj * 32] = v;
    }
}

extern "C" void kernel_launch(void* const* d_in, const int* in_sizes, int n_in,
                              void* d_out, int out_size, void* d_ws, size_t ws_size,
                              hipStream_t stream) {
    const int* asym = (const int*)d_in[0];
    const int* resi = (const int*)d_in[1];
    const int* ent  = (const int*)d_in[2];
    const int* sym  = (const int*)d_in[3];
    const int* tok  = (const int*)d_in[4];
    const float* W  = (const float*)d_in[5];
    float* out = (float*)d_out;

    const int N = in_sizes[0];          // B*N with B=1 (N=1024)

    // K1: 792 rows * 32 float4 = 25344 threads = 99 blocks
    build_combo<<<99, BLOCK, 0, stream>>>(W, (float4*)d_ws);

    // K2: (j-tile, i) grid; same-stream ordering makes C visible to K2
    dim3 grid(N / TJ, N);
    relpos_stream<<<grid, BLOCK, 0, stream>>>(
        asym, resi, ent, sym, tok, (const char*)d_ws, out, N);
}

// Round 5
// 533.341 us; speedup vs baseline: 1.1864x; 1.0073x over previous
//
#include <hip/hip_runtime.h>

// RelativePositionEncoding (AF3-style), B=1, N=1024, C_Z=128. HBM-write-bound:
// 537 MB out, write roofline ~85 us @ 6.3 TB/s. Harness adds ~425 us/iter of
// poison-fill overhead (2 GiB d_ws + 537 MB d_out) visible in rocprof.
//
// Fused-table algebra (verified absmax=0 R1-R3): d_tok != 65 iff
// (same_chain && same_res) and then d_res==32; d_chain != 5 iff same_ent.
// out[i,j,:] is one of only 132*6 = 792 distinct rows:
//   out[i,j,:] = C[row*6 + crow], with
//     row  < 66 : W_pos[32]  + W_tok[row]        (same chain+res, dt=row)
//     row >= 66 : W_pos[row-66] + W_tok[65]      (dr = row-66; diff chain -> 131)
//     crow < 5  : W_ch[crow] + w_ent             (same entity)
//     crow == 5 : W_ch[5]
//
// R5 = R4 with the nt-store compile fix: __builtin_nontemporal_store requires
// a native clang vector type, not HIP_vector_type<float,4>. Stores are
// non-temporal so the 537 MB write stream doesn't evict the 405 KB C table
// from L2 (gather-load side wants C L2/L1-resident).

#define RMAX 32
#define SMAX 2
#define TJ 512
#define BLOCK 256

typedef float v4f __attribute__((ext_vector_type(4)));

// ---- K1: build the 792 x 128 combined-row table in d_ws ----
__global__ __launch_bounds__(BLOCK) void build_combo(
    const float* __restrict__ W, float4* __restrict__ C)
{
    const int t  = blockIdx.x * BLOCK + threadIdx.x;
    const int rc = t >> 5;          // combined row 0..791
    const int cc = t & 31;          // float4 group 0..31
    const int r  = rc / 6;          // 0..131
    const int c  = rc - r * 6;      // 0..5

    const float4* __restrict__ W4 = reinterpret_cast<const float4*>(W);
    // W rows: W_pos 0..65, W_tok 66..131, w_ent 132, W_ch 133..138.
    float4 a, b;
    if (r < 66) { a = W4[32 * 32 + cc];       b = W4[(66 + r) * 32 + cc]; }
    else        { a = W4[(r - 66) * 32 + cc]; b = W4[131 * 32 + cc];      }
    float4 d;
    if (c < 5) {
        const float4 e = W4[(133 + c) * 32 + cc];
        const float4 f = W4[132 * 32 + cc];
        d = make_float4(e.x + f.x, e.y + f.y, e.z + f.z, e.w + f.w);
    } else {
        d = W4[138 * 32 + cc];
    }
    C[rc * 32 + cc] = make_float4(a.x + b.x + d.x, a.y + b.y + d.y,
                                  a.z + b.z + d.z, a.w + b.w + d.w);
}

// ---- K2: stream the output; pure gather-memcpy hot loop, nt stores ----
__global__ __launch_bounds__(BLOCK) void relpos_stream(
    const int* __restrict__ asym, const int* __restrict__ resi,
    const int* __restrict__ ent,  const int* __restrict__ sym,
    const int* __restrict__ tok,  const char* __restrict__ Cbytes,
    float* __restrict__ out, int N)
{
    __shared__ int sAddr[TJ];      // per-j byte offset into C (2 KB)

    const int tid = threadIdx.x;
    const int i   = blockIdx.y;
    const int j0  = blockIdx.x * TJ;

    // --- index build: (row*6+crow)*512 byte offsets for this j-tile ---
    const int ai = asym[i], ri = resi[i], ei = ent[i], si = sym[i], ti = tok[i];
    for (int t = tid; t < TJ; t += BLOCK) {
        const int j = j0 + t;
        const int aj = asym[j], rj = resi[j], ej = ent[j], sj = sym[j], tj = tok[j];
        int row;
        if (ai == aj) {
            if (ri == rj) {
                int dt = ti - tj + RMAX;
                dt = dt < 0 ? 0 : (dt > 2 * RMAX ? 2 * RMAX : dt);
                row = dt;
            } else {
                int dr = ri - rj + RMAX;
                dr = dr < 0 ? 0 : (dr > 2 * RMAX ? 2 * RMAX : dr);
                row = 66 + dr;
            }
        } else {
            row = 131;
        }
        int crow;
        if (ei == ej) {
            int dc = si - sj + SMAX;
            dc = dc < 0 ? 0 : (dc > 2 * SMAX ? 2 * SMAX : dc);
            crow = dc;
        } else {
            crow = 5;
        }
        sAddr[t] = (row * 6 + crow) << 9;   // *512 bytes per combined row
    }
    __syncthreads();

    // --- stream: wave = 2 rows x 512 B = contiguous 1024 B nt stores ---
    const int cc = tid & 31;   // float4 group within row
    const int jl = tid >> 5;   // 0..7
    v4f* __restrict__ out4 = reinterpret_cast<v4f*>(out);
    const size_t base = ((size_t)i * N + j0) * 32 + cc;

    #pragma unroll 8
    for (int jj = jl; jj < TJ; jj += 8) {
        const int off = sAddr[jj];
        const v4f v = *reinterpret_cast<const v4f*>(Cbytes + off + (cc << 4));
        __builtin_nontemporal_store(v, out4 + base + (size_t)jj * 32);
    }
}

extern "C" void kernel_launch(void* const* d_in, const int* in_sizes, int n_in,
                              void* d_out, int out_size, void* d_ws, size_t ws_size,
                              hipStream_t stream) {
    const int* asym = (const int*)d_in[0];
    const int* resi = (const int*)d_in[1];
    const int* ent  = (const int*)d_in[2];
    const int* sym  = (const int*)d_in[3];
    const int* tok  = (const int*)d_in[4];
    const float* W  = (const float*)d_in[5];
    float* out = (float*)d_out;

    const int N = in_sizes[0];          // B*N with B=1 (N=1024)

    // K1: 792 rows * 32 float4 = 25344 threads = 99 blocks
    build_combo<<<99, BLOCK, 0, stream>>>(W, (float4*)d_ws);

    // K2: (j-tile, i) grid; same-stream ordering makes C visible to K2
    dim3 grid(N / TJ, N);
    relpos_stream<<<grid, BLOCK, 0, stream>>>(
        asym, resi, ent, sym, tok, (const char*)d_ws, out, N);
}